// Round 8
// baseline (194.075 us; speedup 1.0000x reference)
//
#include <hip/hip_runtime.h>
#include <hip/hip_bf16.h>
#include <cstdint>

#define N_NODES 50000
#define N_EDGES 1600000
#define EE (N_EDGES + N_NODES)
#define BSH 7
#define BSIZE 128
#define NBUCKET ((N_NODES + BSIZE - 1) >> BSH)   // 391
#define CSH 13
#define CAP 8192                                  // pow2 bucket capacity (mean fill 4224, sd ~65)
#define BIN_BLOCKS 403                            // ceil(EE/4096) -- one chunk per block
#define GEMM_BLOCKS 3125                          // 3125*16 == 50000

// HISTORY (hard-won, do not regress):
//  r4: per-edge direct scatter -> 102MB WRITE_SIZE (partial-line write amp). Two-stage LDS
//      binning IS the write-coalescer.
//  r5: NBUCKET=1563 (2.6-edge runs) -> 50MB WRITE_SIZE, +8us. NBUCKET=391/CHUNK=4096
//      (10.5-edge, 42B runs) is load-bearing.
//  r7: quarter-split sort with cross-block global cursors -> post-timing divergence
//      (first launch OK, later launches off by 7e-2). Root cause never isolated.
//      RULE: every read must be rebuilt this-launch from the single zeroed root (bcur);
//      no cross-block cursor coordination in the sort.

__device__ __forceinline__ float lrelu(float x, float s) { return x >= 0.f ? x : s * x; }
__device__ __forceinline__ float bflo(uint32_t v) { return __uint_as_float(v << 16); }
__device__ __forceinline__ float bfhi(uint32_t v) { return __uint_as_float(v & 0xFFFF0000u); }
__device__ __forceinline__ uint32_t packbf(float a, float b) {
    uint32_t ua = __float_as_uint(a), ub = __float_as_uint(b);
    ua += 0x7FFF + ((ua >> 16) & 1);
    ub += 0x7FFF + ((ub >> 16) & 1);
    return (ua >> 16) | (ub & 0xFFFF0000u);
}
__device__ __forceinline__ float rdlane(float v, int l) {
    return __uint_as_float(__builtin_amdgcn_readlane(__float_as_uint(v), l));
}

// -------- Fused: edge binning (blocks 0..402, dispatched first) + layer-1 GEMM (rest) --------
__global__ __launch_bounds__(256) void k_pre(
    const float* __restrict__ x, const float* __restrict__ W1,
    const float* __restrict__ as_w, const float* __restrict__ ad_w,
    uint32_t* __restrict__ h1b, float* __restrict__ as1, float* __restrict__ ad1,
    const int* __restrict__ src, const int* __restrict__ dst,
    int* __restrict__ bcur, uint32_t* __restrict__ binned) {
    if (blockIdx.x < BIN_BLOCKS) {
        __shared__ int lcnt[NBUCKET];
        __shared__ int lbase[NBUCKET];
        const int T = 16;
        for (int i = threadIdx.x; i < NBUCKET; i += 256) lcnt[i] = 0;
        __syncthreads();
        uint32_t pv[T];
        uint32_t pm[T];
        int base = blockIdx.x * (256 * T);
        if (base + 256 * T <= N_EDGES) {
            // fast path: pure-edge chunk, int4 loads (4 edges per load)
            const int4* s4 = (const int4*)(src + base);
            const int4* d4 = (const int4*)(dst + base);
#pragma unroll
            for (int k = 0; k < 4; k++) {
                int4 sv = s4[threadIdx.x + k * 256];
                int4 dv = d4[threadIdx.x + k * 256];
                int ss[4] = {sv.x, sv.y, sv.z, sv.w};
                int dd[4] = {dv.x, dv.y, dv.z, dv.w};
#pragma unroll
                for (int j = 0; j < 4; j++) {
                    int b = dd[j] >> BSH;
                    int r = atomicAdd(&lcnt[b], 1);
                    pv[k * 4 + j] = (uint32_t)ss[j] | ((uint32_t)(dd[j] & (BSIZE - 1)) << 16);
                    pm[k * 4 + j] = (uint32_t)r | ((uint32_t)b << 16);
                }
            }
        } else {
#pragma unroll
            for (int k = 0; k < T; k++) {
                int e = base + ((k & 3) * 4 + (k >> 2)) * 256 + threadIdx.x;  // any order ok
                pm[k] = 0xFFFFFFFFu;
                if (e < EE) {
                    int s, d;
                    if (e < N_EDGES) { s = src[e]; d = dst[e]; } else { s = e - N_EDGES; d = s; }
                    int b = d >> BSH;
                    int r = atomicAdd(&lcnt[b], 1);
                    pv[k] = (uint32_t)s | ((uint32_t)(d & (BSIZE - 1)) << 16);
                    pm[k] = (uint32_t)r | ((uint32_t)b << 16);
                }
            }
        }
        __syncthreads();
        for (int i = threadIdx.x; i < NBUCKET; i += 256) {
            int c = lcnt[i];
            if (c) lbase[i] = atomicAdd(&bcur[i], c);
        }
        __syncthreads();
#pragma unroll
        for (int k = 0; k < T; k++) {
            if (pm[k] != 0xFFFFFFFFu) {
                int b = pm[k] >> 16, r = pm[k] & 0xFFFF;
                binned[((size_t)b << CSH) + lbase[b] + r] = pv[k];
            }
        }
        return;
    }
    // ---- layer-1 GEMM half: coalesced x load + readlane broadcast ----
    int c = threadIdx.x & 63;
    int wv = threadIdx.x >> 6;
    float wreg[64];
#pragma unroll
    for (int k = 0; k < 64; k++) wreg[k] = W1[k * 64 + c];
    float aw = as_w[c];
    float dw = ad_w[c];
    int base = (blockIdx.x - BIN_BLOCKS) * 16 + wv * 4;
#pragma unroll
    for (int r = 0; r < 4; r++) {
        int n = base + r;
        float xr = x[n * 64 + c];
        float a0 = 0.f, a1 = 0.f, a2 = 0.f, a3 = 0.f;
#pragma unroll
        for (int k = 0; k < 64; k += 4) {
            a0 = fmaf(rdlane(xr, k),     wreg[k],     a0);
            a1 = fmaf(rdlane(xr, k + 1), wreg[k + 1], a1);
            a2 = fmaf(rdlane(xr, k + 2), wreg[k + 2], a2);
            a3 = fmaf(rdlane(xr, k + 3), wreg[k + 3], a3);
        }
        float acc = (a0 + a1) + (a2 + a3);
        float other = __shfl_xor(acc, 1, 64);
        if (!(c & 1)) h1b[n * 32 + (c >> 1)] = packbf(acc, other);
        float asv = acc * aw;
        float adv = acc * dw;
#pragma unroll
        for (int off = 1; off < 16; off <<= 1) {
            asv += __shfl_xor(asv, off, 64);
            adv += __shfl_xor(adv, off, 64);
        }
        if ((c & 15) == 0) { as1[n * 4 + (c >> 4)] = asv; ad1[n * 4 + (c >> 4)] = adv; }
    }
}

// -------- Phase B: rank-capture counting sort -> u16 CSR src indices --------
// rowdesc[node] = off(13b) | deg(<<13);  esrc[pos] = src (u16)
// Scan: wave-0 shuffle (pair-sum 128 entries into 64 lanes, 6 shfl_up steps, 2 barriers)
// replaces the 14-barrier Hillis-Steele -- intra-block change only.
__global__ __launch_bounds__(512) void kB_sort(const int* __restrict__ bcur, const uint32_t* __restrict__ binned,
                                               int* __restrict__ rowdesc, unsigned short* __restrict__ esrc) {
    int b = blockIdx.x, tid = threadIdx.x, wv = tid >> 6;
    int p0 = b << CSH;
    int L = bcur[b];
    __shared__ int cnt8[8][BSIZE];     // per-wave histograms
    __shared__ int wbase[8][BSIZE];
    __shared__ int shs[BSIZE];
    for (int i = tid; i < 8 * BSIZE; i += 512) ((int*)cnt8)[i] = 0;
    __syncthreads();

    uint32_t pv[16];
    unsigned short rk[16];
#pragma unroll
    for (int k = 0; k < 16; k++) {
        int i = tid + k * 512;
        if (i < L) {
            uint32_t v = binned[p0 + i];
            pv[k] = v;
            rk[k] = (unsigned short)atomicAdd(&cnt8[wv][(v >> 16) & (BSIZE - 1)], 1);
        }
    }
    __syncthreads();

    int tot = 0;
    if (tid < BSIZE) {
#pragma unroll
        for (int w = 0; w < 8; w++) tot += cnt8[w][tid];
        shs[tid] = tot;
    }
    __syncthreads();
    if (tid < 64) {                    // wave 0: exclusive scan of 128 totals via pair-sum
        int t0 = shs[2 * tid], t1 = shs[2 * tid + 1];
        int pair = t0 + t1;
        int incl = pair;
#pragma unroll
        for (int off = 1; off < 64; off <<= 1) {
            int t = __shfl_up(incl, off, 64);
            if (tid >= off) incl += t;
        }
        int exclp = incl - pair;
        shs[2 * tid] = exclp;
        shs[2 * tid + 1] = exclp + t0;
    }
    __syncthreads();
    if (tid < BSIZE) {
        int excl = shs[tid];           // tot still live in register
        int node = (b << BSH) + tid;
        if (node < N_NODES) rowdesc[node] = excl | (tot << 13);
        int wb = excl;
#pragma unroll
        for (int w = 0; w < 8; w++) { wbase[w][tid] = wb; wb += cnt8[w][tid]; }
    }
    __syncthreads();

#pragma unroll
    for (int k = 0; k < 16; k++) {
        int i = tid + k * 512;
        if (i < L) {
            uint32_t v = pv[k];
            int dl = (v >> 16) & (BSIZE - 1);
            esrc[p0 + wbase[wv][dl] + (int)rk[k]] = (unsigned short)(v & 0xFFFF);
        }
    }
}

// -------- Layer 1 aggregation (inline weights) + fused L2 GEMM: 8 edges/iter --------
// 12500 blocks, 1 node/wave. Masked tail lanes CLAMP s to 0 (never mask-by-weight a NaN gather).
__global__ __launch_bounds__(256) void k_aggr1f(
    const int* __restrict__ rowdesc, const unsigned short* __restrict__ esrc,
    const float* __restrict__ as1, const float* __restrict__ ad1,
    const uint32_t* __restrict__ h1b,
    const float* __restrict__ b1, const float* __restrict__ W2,
    const float* __restrict__ as2w, const float* __restrict__ ad2w,
    uint32_t* __restrict__ h2b, float* __restrict__ as2, float* __restrict__ ad2) {
    int n = blockIdx.x * 4 + (threadIdx.x >> 6);
    int lane = threadIdx.x & 63;
    int md = rowdesc[n];
    int begin = ((n >> BSH) << CSH) + (md & (CAP - 1));
    int deg = md >> 13;

    int slot = lane >> 3, cl = lane & 7;   // edge slot = slot; lane covers channels 8cl..8cl+7
    int hc = cl >> 1;                      // head of these channels
    float ad1h = ad1[n * 4 + hc];

    const uint4* h1b4 = (const uint4*)h1b;
    float a0 = 0.f, a1 = 0.f, a2 = 0.f, a3 = 0.f, a4 = 0.f, a5 = 0.f, a6 = 0.f, a7 = 0.f, dsum = 0.f;

    int iters = (deg + 7) >> 3;
#pragma unroll 4
    for (int it = 0; it < iters; it++) {
        int idx = it * 8 + slot;
        bool ok = idx < deg;
        int s = ok ? (int)esrc[begin + idx] : 0;   // clamp: masked lanes gather node 0
        float e = as1[s * 4 + hc] + ad1h;
        float w = __expf(e >= 0.f ? e : 0.2f * e);
        w = ok ? w : 0.f;
        uint4 v = h1b4[s * 8 + cl];
        dsum += w;
        a0 += w * bflo(v.x); a1 += w * bfhi(v.x);
        a2 += w * bflo(v.y); a3 += w * bfhi(v.y);
        a4 += w * bflo(v.z); a5 += w * bfhi(v.z);
        a6 += w * bflo(v.w); a7 += w * bfhi(v.w);
    }
#pragma unroll
    for (int off = 8; off <= 32; off <<= 1) {
        a0 += __shfl_xor(a0, off, 64); a1 += __shfl_xor(a1, off, 64);
        a2 += __shfl_xor(a2, off, 64); a3 += __shfl_xor(a3, off, 64);
        a4 += __shfl_xor(a4, off, 64); a5 += __shfl_xor(a5, off, 64);
        a6 += __shfl_xor(a6, off, 64); a7 += __shfl_xor(a7, off, 64);
        dsum += __shfl_xor(dsum, off, 64);
    }
    float dinv = 1.f / dsum;               // full denom of head hc (deg>=1 via self-loop)

    float4 bb0 = *(const float4*)(b1 + 8 * cl);
    float4 bb1 = *(const float4*)(b1 + 8 * cl + 4);
    float act0 = lrelu(a0 * dinv + bb0.x, 0.01f);
    float act1 = lrelu(a1 * dinv + bb0.y, 0.01f);
    float act2 = lrelu(a2 * dinv + bb0.z, 0.01f);
    float act3 = lrelu(a3 * dinv + bb0.w, 0.01f);
    float act4 = lrelu(a4 * dinv + bb1.x, 0.01f);
    float act5 = lrelu(a5 * dinv + bb1.y, 0.01f);
    float act6 = lrelu(a6 * dinv + bb1.z, 0.01f);
    float act7 = lrelu(a7 * dinv + bb1.w, 0.01f);

    // fused L2 GEMM: lane (kg, co) sums k = 16kg..16kg+15 for output channel co
    int co = lane & 15, kg = lane >> 4;
    int l0 = 2 * kg, l1 = 2 * kg + 1;
    const float* w2r = W2 + (16 * kg) * 16 + co;
    float g = 0.f;
    g = fmaf(__shfl(act0, l0, 64), w2r[0 * 16],  g);
    g = fmaf(__shfl(act1, l0, 64), w2r[1 * 16],  g);
    g = fmaf(__shfl(act2, l0, 64), w2r[2 * 16],  g);
    g = fmaf(__shfl(act3, l0, 64), w2r[3 * 16],  g);
    g = fmaf(__shfl(act4, l0, 64), w2r[4 * 16],  g);
    g = fmaf(__shfl(act5, l0, 64), w2r[5 * 16],  g);
    g = fmaf(__shfl(act6, l0, 64), w2r[6 * 16],  g);
    g = fmaf(__shfl(act7, l0, 64), w2r[7 * 16],  g);
    g = fmaf(__shfl(act0, l1, 64), w2r[8 * 16],  g);
    g = fmaf(__shfl(act1, l1, 64), w2r[9 * 16],  g);
    g = fmaf(__shfl(act2, l1, 64), w2r[10 * 16], g);
    g = fmaf(__shfl(act3, l1, 64), w2r[11 * 16], g);
    g = fmaf(__shfl(act4, l1, 64), w2r[12 * 16], g);
    g = fmaf(__shfl(act5, l1, 64), w2r[13 * 16], g);
    g = fmaf(__shfl(act6, l1, 64), w2r[14 * 16], g);
    g = fmaf(__shfl(act7, l1, 64), w2r[15 * 16], g);
    g += __shfl_xor(g, 16, 64);
    g += __shfl_xor(g, 32, 64);
    // h2 packed bf16: even lanes <16 write channels (lane, lane+1)
    float godd = __shfl_xor(g, 1, 64);
    if (lane < 16 && !(lane & 1)) h2b[n * 8 + (lane >> 1)] = packbf(g, godd);
    float asv = g * as2w[co];
    float adv2 = g * ad2w[co];
#pragma unroll
    for (int off = 1; off < 16; off <<= 1) {
        asv += __shfl_xor(asv, off, 64);
        adv2 += __shfl_xor(adv2, off, 64);
    }
    if (lane == 0) { as2[n] = asv; ad2[n] = adv2; }
}

// -------- Layer 2 aggregation (inline weights, bf16 h2) + final linear: 8 edges/iter --------
__global__ __launch_bounds__(256) void k_aggr2(
    const int* __restrict__ rowdesc, const unsigned short* __restrict__ esrc,
    const float* __restrict__ as2, const float* __restrict__ ad2,
    const uint32_t* __restrict__ h2b,
    const float* __restrict__ b2, const float* __restrict__ Wo,
    const float* __restrict__ bo, float* __restrict__ out) {
    int n = blockIdx.x * 4 + (threadIdx.x >> 6);
    int lane = threadIdx.x & 63;
    int md = rowdesc[n];
    int begin = ((n >> BSH) << CSH) + (md & (CAP - 1));
    int deg = md >> 13;
    float adv = ad2[n];

    int slot = lane >> 3, c2 = lane & 7;   // lane covers channels 2c2, 2c2+1
    float acc0 = 0.f, acc1 = 0.f, dsum = 0.f;

    int iters = (deg + 7) >> 3;
#pragma unroll 4
    for (int it = 0; it < iters; it++) {
        int idx = it * 8 + slot;
        bool ok = idx < deg;
        int s = ok ? (int)esrc[begin + idx] : 0;    // clamp: masked lanes gather node 0
        float e = as2[s] + adv;
        float w = __expf(e >= 0.f ? e : 0.2f * e);
        w = ok ? w : 0.f;
        uint32_t hv = h2b[s * 8 + c2];
        acc0 += w * bflo(hv);
        acc1 += w * bfhi(hv);
        dsum += w;
    }
#pragma unroll
    for (int off = 8; off <= 32; off <<= 1) {
        acc0 += __shfl_xor(acc0, off, 64);
        acc1 += __shfl_xor(acc1, off, 64);
        dsum += __shfl_xor(dsum, off, 64);
    }
    float v0 = lrelu(acc0 / dsum + b2[2 * c2], 0.01f) * Wo[2 * c2];
    float v1 = lrelu(acc1 / dsum + b2[2 * c2 + 1], 0.01f) * Wo[2 * c2 + 1];
    float y = v0 + v1;
    y += __shfl_xor(y, 1, 64);
    y += __shfl_xor(y, 2, 64);
    y += __shfl_xor(y, 4, 64);
    if (lane == 0) out[n] = y + bo[0];
}

extern "C" void kernel_launch(void* const* d_in, const int* in_sizes, int n_in,
                              void* d_out, int out_size, void* d_ws, size_t ws_size,
                              hipStream_t stream) {
    const float* x    = (const float*)d_in[0];
    const int*   ei   = (const int*)d_in[1];
    const float* W1   = (const float*)d_in[2];
    const float* as1w = (const float*)d_in[3];
    const float* ad1w = (const float*)d_in[4];
    const float* b1   = (const float*)d_in[5];
    const float* W2   = (const float*)d_in[6];
    const float* as2w = (const float*)d_in[7];
    const float* ad2w = (const float*)d_in[8];
    const float* b2   = (const float*)d_in[9];
    const float* Wo   = (const float*)d_in[10];
    const float* bo   = (const float*)d_in[11];
    float* out = (float*)d_out;

    const int* srcp = ei;
    const int* dstp = ei + N_EDGES;

    char* p = (char*)d_ws;
    auto alloc = [&](size_t bytes) -> char* {
        char* r = p;
        p += (bytes + 255) / 256 * 256;
        return r;
    };
    // All gather indices s are real node ids (<50000) or clamped to 0 -> every
    // gather lands inside fully-initialized arrays; no pad-dependence.
    int*            bcur    = (int*)alloc((size_t)(NBUCKET + 1) * 4);
    int*            rowdesc = (int*)alloc((size_t)N_NODES * 4);
    uint32_t*       binned  = (uint32_t*)alloc((size_t)NBUCKET * CAP * 4);
    unsigned short* esrc    = (unsigned short*)alloc((size_t)NBUCKET * CAP * 2 + 256);
    uint32_t*       h2b     = (uint32_t*)alloc((size_t)N_NODES * 8 * 4);
    uint32_t*       h1b     = (uint32_t*)alloc((size_t)N_NODES * 32 * 4);
    float*          as1     = (float*)alloc((size_t)N_NODES * 4 * 4);
    float*          ad1     = (float*)alloc((size_t)N_NODES * 4 * 4);
    float*          as2     = (float*)alloc((size_t)N_NODES * 4);
    float*          ad2     = (float*)alloc((size_t)N_NODES * 4);

    hipMemsetAsync(bcur, 0, (size_t)(NBUCKET + 1) * 4, stream);

    k_pre<<<BIN_BLOCKS + GEMM_BLOCKS, 256, 0, stream>>>(x, W1, as1w, ad1w, h1b, as1, ad1,
                                                        srcp, dstp, bcur, binned);
    kB_sort<<<NBUCKET, 512, 0, stream>>>(bcur, binned, rowdesc, esrc);
    k_aggr1f<<<N_NODES / 4, 256, 0, stream>>>(rowdesc, esrc, as1, ad1, h1b, b1, W2, as2w, ad2w,
                                              h2b, as2, ad2);
    k_aggr2<<<N_NODES / 4, 256, 0, stream>>>(rowdesc, esrc, as2, ad2, h2b, b2, Wo, bo, out);
}

// Round 9
// 192.776 us; speedup vs baseline: 1.0067x; 1.0067x over previous
//
#include <hip/hip_runtime.h>
#include <hip/hip_bf16.h>
#include <cstdint>

#define N_NODES 50000
#define N_EDGES 1600000
#define EE (N_EDGES + N_NODES)
#define BSH 7
#define BSIZE 128
#define NBUCKET ((N_NODES + BSIZE - 1) >> BSH)   // 391
#define CSH 13
#define CAP 8192                                  // pow2 bucket capacity (mean fill 4224, sd ~65)
#define BIN_BLOCKS 403                            // ceil(EE/4096) -- one chunk per block
#define SPLIT 24992                               // GEMM node split: K1 does [0,SPLIT), K2 the rest
#define K1_GEMM_BLOCKS (SPLIT / 16)               // 1562 (16 nodes per 256-thr block)
#define K2_GEMM_BLOCKS ((N_NODES - SPLIT + 31) / 32)   // 782 (32 nodes per 512-thr block)

// HISTORY (hard-won, do not regress):
//  r4: per-edge direct scatter -> 102MB WRITE_SIZE (partial-line write amp). Two-stage LDS
//      binning IS the write-coalescer.
//  r5: NBUCKET=1563 (2.6-edge runs) -> 50MB WRITE_SIZE, +8us. NBUCKET=391/CHUNK=4096
//      (10.5-edge, 42B runs) is load-bearing.
//  r7: quarter-split sort with cross-block global cursors -> post-timing divergence.
//      RULE: every read rebuilt this-launch from the single zeroed root (bcur);
//      no cross-block cursor coordination in the sort.
//  r8: shuffle scan neutral -> sort is not barrier-bound; kB_sort wall is read+scatter.
//  r9: overlap sort with half the GEMM (scheduling only; inner bodies unchanged).

__device__ __forceinline__ float lrelu(float x, float s) { return x >= 0.f ? x : s * x; }
__device__ __forceinline__ float bflo(uint32_t v) { return __uint_as_float(v << 16); }
__device__ __forceinline__ float bfhi(uint32_t v) { return __uint_as_float(v & 0xFFFF0000u); }
__device__ __forceinline__ uint32_t packbf(float a, float b) {
    uint32_t ua = __float_as_uint(a), ub = __float_as_uint(b);
    ua += 0x7FFF + ((ua >> 16) & 1);
    ub += 0x7FFF + ((ub >> 16) & 1);
    return (ua >> 16) | (ub & 0xFFFF0000u);
}
__device__ __forceinline__ float rdlane(float v, int l) {
    return __uint_as_float(__builtin_amdgcn_readlane(__float_as_uint(v), l));
}

// Shared GEMM body: one wave computes 4 nodes starting at `base` (all < N_NODES).
__device__ __forceinline__ void gemm1_wave(
    int base, int c,
    const float* __restrict__ x, const float* __restrict__ W1,
    const float* __restrict__ as_w, const float* __restrict__ ad_w,
    uint32_t* __restrict__ h1b, float* __restrict__ as1, float* __restrict__ ad1) {
    float wreg[64];
#pragma unroll
    for (int k = 0; k < 64; k++) wreg[k] = W1[k * 64 + c];
    float aw = as_w[c];
    float dw = ad_w[c];
#pragma unroll
    for (int r = 0; r < 4; r++) {
        int n = base + r;
        float xr = x[n * 64 + c];
        float a0 = 0.f, a1 = 0.f, a2 = 0.f, a3 = 0.f;
#pragma unroll
        for (int k = 0; k < 64; k += 4) {
            a0 = fmaf(rdlane(xr, k),     wreg[k],     a0);
            a1 = fmaf(rdlane(xr, k + 1), wreg[k + 1], a1);
            a2 = fmaf(rdlane(xr, k + 2), wreg[k + 2], a2);
            a3 = fmaf(rdlane(xr, k + 3), wreg[k + 3], a3);
        }
        float acc = (a0 + a1) + (a2 + a3);
        float other = __shfl_xor(acc, 1, 64);
        if (!(c & 1)) h1b[n * 32 + (c >> 1)] = packbf(acc, other);
        float asv = acc * aw;
        float adv = acc * dw;
#pragma unroll
        for (int off = 1; off < 16; off <<= 1) {
            asv += __shfl_xor(asv, off, 64);
            adv += __shfl_xor(adv, off, 64);
        }
        if ((c & 15) == 0) { as1[n * 4 + (c >> 4)] = asv; ad1[n * 4 + (c >> 4)] = adv; }
    }
}

// -------- K1: edge binning (blocks 0..402, dispatched first) + GEMM nodes [0,SPLIT) --------
__global__ __launch_bounds__(256) void k_pre(
    const float* __restrict__ x, const float* __restrict__ W1,
    const float* __restrict__ as_w, const float* __restrict__ ad_w,
    uint32_t* __restrict__ h1b, float* __restrict__ as1, float* __restrict__ ad1,
    const int* __restrict__ src, const int* __restrict__ dst,
    int* __restrict__ bcur, uint32_t* __restrict__ binned) {
    if (blockIdx.x < BIN_BLOCKS) {
        __shared__ int lcnt[NBUCKET];
        __shared__ int lbase[NBUCKET];
        const int T = 16;
        for (int i = threadIdx.x; i < NBUCKET; i += 256) lcnt[i] = 0;
        __syncthreads();
        uint32_t pv[T];
        uint32_t pm[T];
        int base = blockIdx.x * (256 * T);
        if (base + 256 * T <= N_EDGES) {
            // fast path: pure-edge chunk, int4 loads (4 edges per load)
            const int4* s4 = (const int4*)(src + base);
            const int4* d4 = (const int4*)(dst + base);
#pragma unroll
            for (int k = 0; k < 4; k++) {
                int4 sv = s4[threadIdx.x + k * 256];
                int4 dv = d4[threadIdx.x + k * 256];
                int ss[4] = {sv.x, sv.y, sv.z, sv.w};
                int dd[4] = {dv.x, dv.y, dv.z, dv.w};
#pragma unroll
                for (int j = 0; j < 4; j++) {
                    int b = dd[j] >> BSH;
                    int r = atomicAdd(&lcnt[b], 1);
                    pv[k * 4 + j] = (uint32_t)ss[j] | ((uint32_t)(dd[j] & (BSIZE - 1)) << 16);
                    pm[k * 4 + j] = (uint32_t)r | ((uint32_t)b << 16);
                }
            }
        } else {
#pragma unroll
            for (int k = 0; k < T; k++) {
                int e = base + ((k & 3) * 4 + (k >> 2)) * 256 + threadIdx.x;  // any order ok
                pm[k] = 0xFFFFFFFFu;
                if (e < EE) {
                    int s, d;
                    if (e < N_EDGES) { s = src[e]; d = dst[e]; } else { s = e - N_EDGES; d = s; }
                    int b = d >> BSH;
                    int r = atomicAdd(&lcnt[b], 1);
                    pv[k] = (uint32_t)s | ((uint32_t)(d & (BSIZE - 1)) << 16);
                    pm[k] = (uint32_t)r | ((uint32_t)b << 16);
                }
            }
        }
        __syncthreads();
        for (int i = threadIdx.x; i < NBUCKET; i += 256) {
            int c = lcnt[i];
            if (c) lbase[i] = atomicAdd(&bcur[i], c);
        }
        __syncthreads();
#pragma unroll
        for (int k = 0; k < T; k++) {
            if (pm[k] != 0xFFFFFFFFu) {
                int b = pm[k] >> 16, r = pm[k] & 0xFFFF;
                binned[((size_t)b << CSH) + lbase[b] + r] = pv[k];
            }
        }
        return;
    }
    // ---- GEMM half: nodes [0, SPLIT) ----
    int c = threadIdx.x & 63;
    int wv = threadIdx.x >> 6;
    int base = (blockIdx.x - BIN_BLOCKS) * 16 + wv * 4;       // max 24988 < SPLIT
    gemm1_wave(base, c, x, W1, as_w, ad_w, h1b, as1, ad1);
}

// -------- K2: counting sort (blocks 0..390, dispatched first) + GEMM nodes [SPLIT,N) --------
// Sort blocks (512 thr) run at ~1.5/CU; GEMM blocks backfill the idle issue slots that
// previously made kB_sort pure serial time.
__global__ __launch_bounds__(512) void kB_sort(
    const int* __restrict__ bcur, const uint32_t* __restrict__ binned,
    int* __restrict__ rowdesc, unsigned short* __restrict__ esrc,
    const float* __restrict__ x, const float* __restrict__ W1,
    const float* __restrict__ as_w, const float* __restrict__ ad_w,
    uint32_t* __restrict__ h1b, float* __restrict__ as1, float* __restrict__ ad1) {
    int tid = threadIdx.x;
    if (blockIdx.x >= NBUCKET) {
        // ---- GEMM half: nodes [SPLIT, N_NODES), 8 waves x 4 nodes = 32 nodes/block ----
        int c = tid & 63;
        int wv8 = tid >> 6;
        int base = SPLIT + (blockIdx.x - NBUCKET) * 32 + wv8 * 4;
        if (base >= N_NODES) return;   // wave-uniform tail guard (last block, upper waves)
        gemm1_wave(base, c, x, W1, as_w, ad_w, h1b, as1, ad1);
        return;
    }
    int b = blockIdx.x, wv = tid >> 6;
    int p0 = b << CSH;
    int L = bcur[b];
    __shared__ int cnt8[8][BSIZE];     // per-wave histograms
    __shared__ int wbase[8][BSIZE];
    __shared__ int shs[BSIZE];
    for (int i = tid; i < 8 * BSIZE; i += 512) ((int*)cnt8)[i] = 0;
    __syncthreads();

    uint32_t pv[16];
    unsigned short rk[16];
#pragma unroll
    for (int k = 0; k < 16; k++) {
        int i = tid + k * 512;
        if (i < L) {
            uint32_t v = binned[p0 + i];
            pv[k] = v;
            rk[k] = (unsigned short)atomicAdd(&cnt8[wv][(v >> 16) & (BSIZE - 1)], 1);
        }
    }
    __syncthreads();

    int tot = 0;
    if (tid < BSIZE) {
#pragma unroll
        for (int w = 0; w < 8; w++) tot += cnt8[w][tid];
        shs[tid] = tot;
    }
    __syncthreads();
    if (tid < 64) {                    // wave 0: exclusive scan of 128 totals via pair-sum
        int t0 = shs[2 * tid], t1 = shs[2 * tid + 1];
        int pair = t0 + t1;
        int incl = pair;
#pragma unroll
        for (int off = 1; off < 64; off <<= 1) {
            int t = __shfl_up(incl, off, 64);
            if (tid >= off) incl += t;
        }
        int exclp = incl - pair;
        shs[2 * tid] = exclp;
        shs[2 * tid + 1] = exclp + t0;
    }
    __syncthreads();
    if (tid < BSIZE) {
        int excl = shs[tid];           // tot still live in register
        int node = (b << BSH) + tid;
        if (node < N_NODES) rowdesc[node] = excl | (tot << 13);
        int wb = excl;
#pragma unroll
        for (int w = 0; w < 8; w++) { wbase[w][tid] = wb; wb += cnt8[w][tid]; }
    }
    __syncthreads();

#pragma unroll
    for (int k = 0; k < 16; k++) {
        int i = tid + k * 512;
        if (i < L) {
            uint32_t v = pv[k];
            int dl = (v >> 16) & (BSIZE - 1);
            esrc[p0 + wbase[wv][dl] + (int)rk[k]] = (unsigned short)(v & 0xFFFF);
        }
    }
}

// -------- Layer 1 aggregation (inline weights) + fused L2 GEMM: 8 edges/iter --------
// 12500 blocks, 1 node/wave. Masked tail lanes CLAMP s to 0 (never mask-by-weight a NaN gather).
__global__ __launch_bounds__(256) void k_aggr1f(
    const int* __restrict__ rowdesc, const unsigned short* __restrict__ esrc,
    const float* __restrict__ as1, const float* __restrict__ ad1,
    const uint32_t* __restrict__ h1b,
    const float* __restrict__ b1, const float* __restrict__ W2,
    const float* __restrict__ as2w, const float* __restrict__ ad2w,
    uint32_t* __restrict__ h2b, float* __restrict__ as2, float* __restrict__ ad2) {
    int n = blockIdx.x * 4 + (threadIdx.x >> 6);
    int lane = threadIdx.x & 63;
    int md = rowdesc[n];
    int begin = ((n >> BSH) << CSH) + (md & (CAP - 1));
    int deg = md >> 13;

    int slot = lane >> 3, cl = lane & 7;   // edge slot = slot; lane covers channels 8cl..8cl+7
    int hc = cl >> 1;                      // head of these channels
    float ad1h = ad1[n * 4 + hc];

    const uint4* h1b4 = (const uint4*)h1b;
    float a0 = 0.f, a1 = 0.f, a2 = 0.f, a3 = 0.f, a4 = 0.f, a5 = 0.f, a6 = 0.f, a7 = 0.f, dsum = 0.f;

    int iters = (deg + 7) >> 3;
#pragma unroll 4
    for (int it = 0; it < iters; it++) {
        int idx = it * 8 + slot;
        bool ok = idx < deg;
        int s = ok ? (int)esrc[begin + idx] : 0;   // clamp: masked lanes gather node 0
        float e = as1[s * 4 + hc] + ad1h;
        float w = __expf(e >= 0.f ? e : 0.2f * e);
        w = ok ? w : 0.f;
        uint4 v = h1b4[s * 8 + cl];
        dsum += w;
        a0 += w * bflo(v.x); a1 += w * bfhi(v.x);
        a2 += w * bflo(v.y); a3 += w * bfhi(v.y);
        a4 += w * bflo(v.z); a5 += w * bfhi(v.z);
        a6 += w * bflo(v.w); a7 += w * bfhi(v.w);
    }
#pragma unroll
    for (int off = 8; off <= 32; off <<= 1) {
        a0 += __shfl_xor(a0, off, 64); a1 += __shfl_xor(a1, off, 64);
        a2 += __shfl_xor(a2, off, 64); a3 += __shfl_xor(a3, off, 64);
        a4 += __shfl_xor(a4, off, 64); a5 += __shfl_xor(a5, off, 64);
        a6 += __shfl_xor(a6, off, 64); a7 += __shfl_xor(a7, off, 64);
        dsum += __shfl_xor(dsum, off, 64);
    }
    float dinv = 1.f / dsum;               // full denom of head hc (deg>=1 via self-loop)

    float4 bb0 = *(const float4*)(b1 + 8 * cl);
    float4 bb1 = *(const float4*)(b1 + 8 * cl + 4);
    float act0 = lrelu(a0 * dinv + bb0.x, 0.01f);
    float act1 = lrelu(a1 * dinv + bb0.y, 0.01f);
    float act2 = lrelu(a2 * dinv + bb0.z, 0.01f);
    float act3 = lrelu(a3 * dinv + bb0.w, 0.01f);
    float act4 = lrelu(a4 * dinv + bb1.x, 0.01f);
    float act5 = lrelu(a5 * dinv + bb1.y, 0.01f);
    float act6 = lrelu(a6 * dinv + bb1.z, 0.01f);
    float act7 = lrelu(a7 * dinv + bb1.w, 0.01f);

    // fused L2 GEMM: lane (kg, co) sums k = 16kg..16kg+15 for output channel co
    int co = lane & 15, kg = lane >> 4;
    int l0 = 2 * kg, l1 = 2 * kg + 1;
    const float* w2r = W2 + (16 * kg) * 16 + co;
    float g = 0.f;
    g = fmaf(__shfl(act0, l0, 64), w2r[0 * 16],  g);
    g = fmaf(__shfl(act1, l0, 64), w2r[1 * 16],  g);
    g = fmaf(__shfl(act2, l0, 64), w2r[2 * 16],  g);
    g = fmaf(__shfl(act3, l0, 64), w2r[3 * 16],  g);
    g = fmaf(__shfl(act4, l0, 64), w2r[4 * 16],  g);
    g = fmaf(__shfl(act5, l0, 64), w2r[5 * 16],  g);
    g = fmaf(__shfl(act6, l0, 64), w2r[6 * 16],  g);
    g = fmaf(__shfl(act7, l0, 64), w2r[7 * 16],  g);
    g = fmaf(__shfl(act0, l1, 64), w2r[8 * 16],  g);
    g = fmaf(__shfl(act1, l1, 64), w2r[9 * 16],  g);
    g = fmaf(__shfl(act2, l1, 64), w2r[10 * 16], g);
    g = fmaf(__shfl(act3, l1, 64), w2r[11 * 16], g);
    g = fmaf(__shfl(act4, l1, 64), w2r[12 * 16], g);
    g = fmaf(__shfl(act5, l1, 64), w2r[13 * 16], g);
    g = fmaf(__shfl(act6, l1, 64), w2r[14 * 16], g);
    g = fmaf(__shfl(act7, l1, 64), w2r[15 * 16], g);
    g += __shfl_xor(g, 16, 64);
    g += __shfl_xor(g, 32, 64);
    // h2 packed bf16: even lanes <16 write channels (lane, lane+1)
    float godd = __shfl_xor(g, 1, 64);
    if (lane < 16 && !(lane & 1)) h2b[n * 8 + (lane >> 1)] = packbf(g, godd);
    float asv = g * as2w[co];
    float adv2 = g * ad2w[co];
#pragma unroll
    for (int off = 1; off < 16; off <<= 1) {
        asv += __shfl_xor(asv, off, 64);
        adv2 += __shfl_xor(adv2, off, 64);
    }
    if (lane == 0) { as2[n] = asv; ad2[n] = adv2; }
}

// -------- Layer 2 aggregation (inline weights, bf16 h2) + final linear: 8 edges/iter --------
__global__ __launch_bounds__(256) void k_aggr2(
    const int* __restrict__ rowdesc, const unsigned short* __restrict__ esrc,
    const float* __restrict__ as2, const float* __restrict__ ad2,
    const uint32_t* __restrict__ h2b,
    const float* __restrict__ b2, const float* __restrict__ Wo,
    const float* __restrict__ bo, float* __restrict__ out) {
    int n = blockIdx.x * 4 + (threadIdx.x >> 6);
    int lane = threadIdx.x & 63;
    int md = rowdesc[n];
    int begin = ((n >> BSH) << CSH) + (md & (CAP - 1));
    int deg = md >> 13;
    float adv = ad2[n];

    int slot = lane >> 3, c2 = lane & 7;   // lane covers channels 2c2, 2c2+1
    float acc0 = 0.f, acc1 = 0.f, dsum = 0.f;

    int iters = (deg + 7) >> 3;
#pragma unroll 4
    for (int it = 0; it < iters; it++) {
        int idx = it * 8 + slot;
        bool ok = idx < deg;
        int s = ok ? (int)esrc[begin + idx] : 0;    // clamp: masked lanes gather node 0
        float e = as2[s] + adv;
        float w = __expf(e >= 0.f ? e : 0.2f * e);
        w = ok ? w : 0.f;
        uint32_t hv = h2b[s * 8 + c2];
        acc0 += w * bflo(hv);
        acc1 += w * bfhi(hv);
        dsum += w;
    }
#pragma unroll
    for (int off = 8; off <= 32; off <<= 1) {
        acc0 += __shfl_xor(acc0, off, 64);
        acc1 += __shfl_xor(acc1, off, 64);
        dsum += __shfl_xor(dsum, off, 64);
    }
    float v0 = lrelu(acc0 / dsum + b2[2 * c2], 0.01f) * Wo[2 * c2];
    float v1 = lrelu(acc1 / dsum + b2[2 * c2 + 1], 0.01f) * Wo[2 * c2 + 1];
    float y = v0 + v1;
    y += __shfl_xor(y, 1, 64);
    y += __shfl_xor(y, 2, 64);
    y += __shfl_xor(y, 4, 64);
    if (lane == 0) out[n] = y + bo[0];
}

extern "C" void kernel_launch(void* const* d_in, const int* in_sizes, int n_in,
                              void* d_out, int out_size, void* d_ws, size_t ws_size,
                              hipStream_t stream) {
    const float* x    = (const float*)d_in[0];
    const int*   ei   = (const int*)d_in[1];
    const float* W1   = (const float*)d_in[2];
    const float* as1w = (const float*)d_in[3];
    const float* ad1w = (const float*)d_in[4];
    const float* b1   = (const float*)d_in[5];
    const float* W2   = (const float*)d_in[6];
    const float* as2w = (const float*)d_in[7];
    const float* ad2w = (const float*)d_in[8];
    const float* b2   = (const float*)d_in[9];
    const float* Wo   = (const float*)d_in[10];
    const float* bo   = (const float*)d_in[11];
    float* out = (float*)d_out;

    const int* srcp = ei;
    const int* dstp = ei + N_EDGES;

    char* p = (char*)d_ws;
    auto alloc = [&](size_t bytes) -> char* {
        char* r = p;
        p += (bytes + 255) / 256 * 256;
        return r;
    };
    // All gather indices s are real node ids (<50000) or clamped to 0 -> every
    // gather lands inside fully-initialized arrays; no pad-dependence.
    int*            bcur    = (int*)alloc((size_t)(NBUCKET + 1) * 4);
    int*            rowdesc = (int*)alloc((size_t)N_NODES * 4);
    uint32_t*       binned  = (uint32_t*)alloc((size_t)NBUCKET * CAP * 4);
    unsigned short* esrc    = (unsigned short*)alloc((size_t)NBUCKET * CAP * 2 + 256);
    uint32_t*       h2b     = (uint32_t*)alloc((size_t)N_NODES * 8 * 4);
    uint32_t*       h1b     = (uint32_t*)alloc((size_t)N_NODES * 32 * 4);
    float*          as1     = (float*)alloc((size_t)N_NODES * 4 * 4);
    float*          ad1     = (float*)alloc((size_t)N_NODES * 4 * 4);
    float*          as2     = (float*)alloc((size_t)N_NODES * 4);
    float*          ad2     = (float*)alloc((size_t)N_NODES * 4);

    hipMemsetAsync(bcur, 0, (size_t)(NBUCKET + 1) * 4, stream);

    k_pre<<<BIN_BLOCKS + K1_GEMM_BLOCKS, 256, 0, stream>>>(x, W1, as1w, ad1w, h1b, as1, ad1,
                                                           srcp, dstp, bcur, binned);
    kB_sort<<<NBUCKET + K2_GEMM_BLOCKS, 512, 0, stream>>>(bcur, binned, rowdesc, esrc,
                                                          x, W1, as1w, ad1w, h1b, as1, ad1);
    k_aggr1f<<<N_NODES / 4, 256, 0, stream>>>(rowdesc, esrc, as1, ad1, h1b, b1, W2, as2w, ad2w,
                                              h2b, as2, ad2);
    k_aggr2<<<N_NODES / 4, 256, 0, stream>>>(rowdesc, esrc, as2, ad2, h2b, b2, Wo, bo, out);
}

// Round 10
// 185.389 us; speedup vs baseline: 1.0469x; 1.0398x over previous
//
#include <hip/hip_runtime.h>
#include <hip/hip_bf16.h>
#include <cstdint>

#define N_NODES 50000
#define N_EDGES 1600000
#define EE (N_EDGES + N_NODES)
#define BSH 7
#define BSIZE 128
#define NBUCKET ((N_NODES + BSIZE - 1) >> BSH)   // 391
#define CSH 13
#define CAP 8192                                  // pow2 bucket capacity (mean fill 4224, sd ~65)
#define BIN_BLOCKS 403                            // ceil(EE/4096) -- one chunk per block
#define GEMM_BLOCKS 3125                          // 3125*16 == 50000

// HISTORY (hard-won, do not regress):
//  r4: per-edge direct scatter -> 102MB WRITE_SIZE (partial-line write amp). Two-stage LDS
//      binning IS the write-coalescer.
//  r5: NBUCKET=1563 (2.6-edge runs) -> 50MB WRITE_SIZE, +8us. NBUCKET=391/CHUNK=4096
//      (10.5-edge, 42B runs) is load-bearing.
//  r7: cross-block global cursors in the sort -> post-timing divergence. RULE: every read
//      rebuilt this-launch from the single zeroed root (bcur); no cross-block coordination.
//  r8: shuffle scan neutral -> sort is not barrier-bound.
//  r9: sort||GEMM overlap neutral (VGPR merge cost ~ backfill gain). r6 grid is the anchor.
//  r10: aggr loops 2-deep software-pipelined (esrc +2, payload gathers +1) to hide the
//       dependent chain esrc->s->(as1,h1b) that unroll-4 exposed (VALUBusy 62% @ 43us).

__device__ __forceinline__ float lrelu(float x, float s) { return x >= 0.f ? x : s * x; }
__device__ __forceinline__ float bflo(uint32_t v) { return __uint_as_float(v << 16); }
__device__ __forceinline__ float bfhi(uint32_t v) { return __uint_as_float(v & 0xFFFF0000u); }
__device__ __forceinline__ uint32_t packbf(float a, float b) {
    uint32_t ua = __float_as_uint(a), ub = __float_as_uint(b);
    ua += 0x7FFF + ((ua >> 16) & 1);
    ub += 0x7FFF + ((ub >> 16) & 1);
    return (ua >> 16) | (ub & 0xFFFF0000u);
}
__device__ __forceinline__ float rdlane(float v, int l) {
    return __uint_as_float(__builtin_amdgcn_readlane(__float_as_uint(v), l));
}

// -------- Fused: edge binning (blocks 0..402, dispatched first) + layer-1 GEMM (rest) --------
__global__ __launch_bounds__(256) void k_pre(
    const float* __restrict__ x, const float* __restrict__ W1,
    const float* __restrict__ as_w, const float* __restrict__ ad_w,
    uint32_t* __restrict__ h1b, float* __restrict__ as1, float* __restrict__ ad1,
    const int* __restrict__ src, const int* __restrict__ dst,
    int* __restrict__ bcur, uint32_t* __restrict__ binned) {
    if (blockIdx.x < BIN_BLOCKS) {
        __shared__ int lcnt[NBUCKET];
        __shared__ int lbase[NBUCKET];
        const int T = 16;
        for (int i = threadIdx.x; i < NBUCKET; i += 256) lcnt[i] = 0;
        __syncthreads();
        uint32_t pv[T];
        uint32_t pm[T];
        int base = blockIdx.x * (256 * T);
        if (base + 256 * T <= N_EDGES) {
            // fast path: pure-edge chunk, int4 loads (4 edges per load)
            const int4* s4 = (const int4*)(src + base);
            const int4* d4 = (const int4*)(dst + base);
#pragma unroll
            for (int k = 0; k < 4; k++) {
                int4 sv = s4[threadIdx.x + k * 256];
                int4 dv = d4[threadIdx.x + k * 256];
                int ss[4] = {sv.x, sv.y, sv.z, sv.w};
                int dd[4] = {dv.x, dv.y, dv.z, dv.w};
#pragma unroll
                for (int j = 0; j < 4; j++) {
                    int b = dd[j] >> BSH;
                    int r = atomicAdd(&lcnt[b], 1);
                    pv[k * 4 + j] = (uint32_t)ss[j] | ((uint32_t)(dd[j] & (BSIZE - 1)) << 16);
                    pm[k * 4 + j] = (uint32_t)r | ((uint32_t)b << 16);
                }
            }
        } else {
#pragma unroll
            for (int k = 0; k < T; k++) {
                int e = base + ((k & 3) * 4 + (k >> 2)) * 256 + threadIdx.x;  // any order ok
                pm[k] = 0xFFFFFFFFu;
                if (e < EE) {
                    int s, d;
                    if (e < N_EDGES) { s = src[e]; d = dst[e]; } else { s = e - N_EDGES; d = s; }
                    int b = d >> BSH;
                    int r = atomicAdd(&lcnt[b], 1);
                    pv[k] = (uint32_t)s | ((uint32_t)(d & (BSIZE - 1)) << 16);
                    pm[k] = (uint32_t)r | ((uint32_t)b << 16);
                }
            }
        }
        __syncthreads();
        for (int i = threadIdx.x; i < NBUCKET; i += 256) {
            int c = lcnt[i];
            if (c) lbase[i] = atomicAdd(&bcur[i], c);
        }
        __syncthreads();
#pragma unroll
        for (int k = 0; k < T; k++) {
            if (pm[k] != 0xFFFFFFFFu) {
                int b = pm[k] >> 16, r = pm[k] & 0xFFFF;
                binned[((size_t)b << CSH) + lbase[b] + r] = pv[k];
            }
        }
        return;
    }
    // ---- layer-1 GEMM half: coalesced x load + readlane broadcast ----
    int c = threadIdx.x & 63;
    int wv = threadIdx.x >> 6;
    float wreg[64];
#pragma unroll
    for (int k = 0; k < 64; k++) wreg[k] = W1[k * 64 + c];
    float aw = as_w[c];
    float dw = ad_w[c];
    int base = (blockIdx.x - BIN_BLOCKS) * 16 + wv * 4;
#pragma unroll
    for (int r = 0; r < 4; r++) {
        int n = base + r;
        float xr = x[n * 64 + c];
        float a0 = 0.f, a1 = 0.f, a2 = 0.f, a3 = 0.f;
#pragma unroll
        for (int k = 0; k < 64; k += 4) {
            a0 = fmaf(rdlane(xr, k),     wreg[k],     a0);
            a1 = fmaf(rdlane(xr, k + 1), wreg[k + 1], a1);
            a2 = fmaf(rdlane(xr, k + 2), wreg[k + 2], a2);
            a3 = fmaf(rdlane(xr, k + 3), wreg[k + 3], a3);
        }
        float acc = (a0 + a1) + (a2 + a3);
        float other = __shfl_xor(acc, 1, 64);
        if (!(c & 1)) h1b[n * 32 + (c >> 1)] = packbf(acc, other);
        float asv = acc * aw;
        float adv = acc * dw;
#pragma unroll
        for (int off = 1; off < 16; off <<= 1) {
            asv += __shfl_xor(asv, off, 64);
            adv += __shfl_xor(adv, off, 64);
        }
        if ((c & 15) == 0) { as1[n * 4 + (c >> 4)] = asv; ad1[n * 4 + (c >> 4)] = adv; }
    }
}

// -------- Phase B: rank-capture counting sort -> u16 CSR src indices --------
// rowdesc[node] = off(13b) | deg(<<13);  esrc[pos] = src (u16)
__global__ __launch_bounds__(512) void kB_sort(const int* __restrict__ bcur, const uint32_t* __restrict__ binned,
                                               int* __restrict__ rowdesc, unsigned short* __restrict__ esrc) {
    int b = blockIdx.x, tid = threadIdx.x, wv = tid >> 6;
    int p0 = b << CSH;
    int L = bcur[b];
    __shared__ int cnt8[8][BSIZE];     // per-wave histograms
    __shared__ int wbase[8][BSIZE];
    __shared__ int shs[BSIZE];
    for (int i = tid; i < 8 * BSIZE; i += 512) ((int*)cnt8)[i] = 0;
    __syncthreads();

    uint32_t pv[16];
    unsigned short rk[16];
#pragma unroll
    for (int k = 0; k < 16; k++) {
        int i = tid + k * 512;
        if (i < L) {
            uint32_t v = binned[p0 + i];
            pv[k] = v;
            rk[k] = (unsigned short)atomicAdd(&cnt8[wv][(v >> 16) & (BSIZE - 1)], 1);
        }
    }
    __syncthreads();

    int tot = 0;
    if (tid < BSIZE) {
#pragma unroll
        for (int w = 0; w < 8; w++) tot += cnt8[w][tid];
        shs[tid] = tot;
    }
    __syncthreads();
    for (int off = 1; off < BSIZE; off <<= 1) {
        int t = 0;
        if (tid < BSIZE && tid >= off) t = shs[tid - off];
        __syncthreads();
        if (tid < BSIZE && tid >= off) shs[tid] += t;
        __syncthreads();
    }
    if (tid < BSIZE) {
        int excl = shs[tid] - tot;
        int node = (b << BSH) + tid;
        if (node < N_NODES) rowdesc[node] = excl | (tot << 13);
        int wb = excl;
#pragma unroll
        for (int w = 0; w < 8; w++) { wbase[w][tid] = wb; wb += cnt8[w][tid]; }
    }
    __syncthreads();

#pragma unroll
    for (int k = 0; k < 16; k++) {
        int i = tid + k * 512;
        if (i < L) {
            uint32_t v = pv[k];
            int dl = (v >> 16) & (BSIZE - 1);
            esrc[p0 + wbase[wv][dl] + (int)rk[k]] = (unsigned short)(v & 0xFFFF);
        }
    }
}

// -------- Layer 1 aggregation (inline weights) + fused L2 GEMM: pipelined 8 edges/iter ------
// 12500 blocks, 1 node/wave. Masked tail lanes CLAMP s to 0 (never mask-by-weight a NaN gather).
// 2-deep software pipeline: esrc prefetched 2 iters ahead, as1/h1b 1 iter ahead, rotated
// through named scalars (runtime-indexed arrays would spill to scratch).
__global__ __launch_bounds__(256) void k_aggr1f(
    const int* __restrict__ rowdesc, const unsigned short* __restrict__ esrc,
    const float* __restrict__ as1, const float* __restrict__ ad1,
    const uint32_t* __restrict__ h1b,
    const float* __restrict__ b1, const float* __restrict__ W2,
    const float* __restrict__ as2w, const float* __restrict__ ad2w,
    uint32_t* __restrict__ h2b, float* __restrict__ as2, float* __restrict__ ad2) {
    int n = blockIdx.x * 4 + (threadIdx.x >> 6);
    int lane = threadIdx.x & 63;
    int md = rowdesc[n];
    int begin = ((n >> BSH) << CSH) + (md & (CAP - 1));
    int deg = md >> 13;

    int slot = lane >> 3, cl = lane & 7;   // edge slot = slot; lane covers channels 8cl..8cl+7
    int hc = cl >> 1;                      // head of these channels
    float ad1h = ad1[n * 4 + hc];

    const uint4* h1b4 = (const uint4*)h1b;
    float a0 = 0.f, a1 = 0.f, a2 = 0.f, a3 = 0.f, a4 = 0.f, a5 = 0.f, a6 = 0.f, a7 = 0.f, dsum = 0.f;

    int iters = (deg + 7) >> 3;
    // ---- pipeline prologue: edge0 payload + edge1 index in flight ----
    bool ok0 = slot < deg;
    int idx1 = slot + 8;
    bool ok1 = idx1 < deg;
    int s0 = ok0 ? (int)esrc[begin + slot] : 0;
    int s1 = ok1 ? (int)esrc[begin + idx1] : 0;
    float e0 = as1[s0 * 4 + hc];
    uint4 v0 = h1b4[s0 * 8 + cl];
#pragma unroll 2
    for (int it = 0; it < iters; it++) {
        // prefetch: index for it+2, payload for it+1 (clamped -> always safe)
        int idx2 = idx1 + 8;
        bool ok2 = idx2 < deg;
        int s2 = ok2 ? (int)esrc[begin + idx2] : 0;
        float e1 = as1[s1 * 4 + hc];
        uint4 v1 = h1b4[s1 * 8 + cl];
        // compute current (it)
        float e = e0 + ad1h;
        float w = __expf(e >= 0.f ? e : 0.2f * e);
        w = ok0 ? w : 0.f;
        dsum += w;
        a0 += w * bflo(v0.x); a1 += w * bfhi(v0.x);
        a2 += w * bflo(v0.y); a3 += w * bfhi(v0.y);
        a4 += w * bflo(v0.z); a5 += w * bfhi(v0.z);
        a6 += w * bflo(v0.w); a7 += w * bfhi(v0.w);
        // rotate
        e0 = e1; v0 = v1; ok0 = ok1;
        s1 = s2; ok1 = ok2; idx1 = idx2;
    }
#pragma unroll
    for (int off = 8; off <= 32; off <<= 1) {
        a0 += __shfl_xor(a0, off, 64); a1 += __shfl_xor(a1, off, 64);
        a2 += __shfl_xor(a2, off, 64); a3 += __shfl_xor(a3, off, 64);
        a4 += __shfl_xor(a4, off, 64); a5 += __shfl_xor(a5, off, 64);
        a6 += __shfl_xor(a6, off, 64); a7 += __shfl_xor(a7, off, 64);
        dsum += __shfl_xor(dsum, off, 64);
    }
    float dinv = 1.f / dsum;               // full denom of head hc (deg>=1 via self-loop)

    float4 bb0 = *(const float4*)(b1 + 8 * cl);
    float4 bb1 = *(const float4*)(b1 + 8 * cl + 4);
    float act0 = lrelu(a0 * dinv + bb0.x, 0.01f);
    float act1 = lrelu(a1 * dinv + bb0.y, 0.01f);
    float act2 = lrelu(a2 * dinv + bb0.z, 0.01f);
    float act3 = lrelu(a3 * dinv + bb0.w, 0.01f);
    float act4 = lrelu(a4 * dinv + bb1.x, 0.01f);
    float act5 = lrelu(a5 * dinv + bb1.y, 0.01f);
    float act6 = lrelu(a6 * dinv + bb1.z, 0.01f);
    float act7 = lrelu(a7 * dinv + bb1.w, 0.01f);

    // fused L2 GEMM: lane (kg, co) sums k = 16kg..16kg+15 for output channel co
    int co = lane & 15, kg = lane >> 4;
    int l0 = 2 * kg, l1 = 2 * kg + 1;
    const float* w2r = W2 + (16 * kg) * 16 + co;
    float g = 0.f;
    g = fmaf(__shfl(act0, l0, 64), w2r[0 * 16],  g);
    g = fmaf(__shfl(act1, l0, 64), w2r[1 * 16],  g);
    g = fmaf(__shfl(act2, l0, 64), w2r[2 * 16],  g);
    g = fmaf(__shfl(act3, l0, 64), w2r[3 * 16],  g);
    g = fmaf(__shfl(act4, l0, 64), w2r[4 * 16],  g);
    g = fmaf(__shfl(act5, l0, 64), w2r[5 * 16],  g);
    g = fmaf(__shfl(act6, l0, 64), w2r[6 * 16],  g);
    g = fmaf(__shfl(act7, l0, 64), w2r[7 * 16],  g);
    g = fmaf(__shfl(act0, l1, 64), w2r[8 * 16],  g);
    g = fmaf(__shfl(act1, l1, 64), w2r[9 * 16],  g);
    g = fmaf(__shfl(act2, l1, 64), w2r[10 * 16], g);
    g = fmaf(__shfl(act3, l1, 64), w2r[11 * 16], g);
    g = fmaf(__shfl(act4, l1, 64), w2r[12 * 16], g);
    g = fmaf(__shfl(act5, l1, 64), w2r[13 * 16], g);
    g = fmaf(__shfl(act6, l1, 64), w2r[14 * 16], g);
    g = fmaf(__shfl(act7, l1, 64), w2r[15 * 16], g);
    g += __shfl_xor(g, 16, 64);
    g += __shfl_xor(g, 32, 64);
    // h2 packed bf16: even lanes <16 write channels (lane, lane+1)
    float godd = __shfl_xor(g, 1, 64);
    if (lane < 16 && !(lane & 1)) h2b[n * 8 + (lane >> 1)] = packbf(g, godd);
    float asv = g * as2w[co];
    float adv2 = g * ad2w[co];
#pragma unroll
    for (int off = 1; off < 16; off <<= 1) {
        asv += __shfl_xor(asv, off, 64);
        adv2 += __shfl_xor(adv2, off, 64);
    }
    if (lane == 0) { as2[n] = asv; ad2[n] = adv2; }
}

// -------- Layer 2 aggregation (inline weights, bf16 h2) + final linear: pipelined --------
__global__ __launch_bounds__(256) void k_aggr2(
    const int* __restrict__ rowdesc, const unsigned short* __restrict__ esrc,
    const float* __restrict__ as2, const float* __restrict__ ad2,
    const uint32_t* __restrict__ h2b,
    const float* __restrict__ b2, const float* __restrict__ Wo,
    const float* __restrict__ bo, float* __restrict__ out) {
    int n = blockIdx.x * 4 + (threadIdx.x >> 6);
    int lane = threadIdx.x & 63;
    int md = rowdesc[n];
    int begin = ((n >> BSH) << CSH) + (md & (CAP - 1));
    int deg = md >> 13;
    float adv = ad2[n];

    int slot = lane >> 3, c2 = lane & 7;   // lane covers channels 2c2, 2c2+1
    float acc0 = 0.f, acc1 = 0.f, dsum = 0.f;

    int iters = (deg + 7) >> 3;
    bool ok0 = slot < deg;
    int idx1 = slot + 8;
    bool ok1 = idx1 < deg;
    int s0 = ok0 ? (int)esrc[begin + slot] : 0;
    int s1 = ok1 ? (int)esrc[begin + idx1] : 0;
    float e0 = as2[s0];
    uint32_t h0 = h2b[s0 * 8 + c2];
#pragma unroll 2
    for (int it = 0; it < iters; it++) {
        int idx2 = idx1 + 8;
        bool ok2 = idx2 < deg;
        int s2 = ok2 ? (int)esrc[begin + idx2] : 0;
        float e1 = as2[s1];
        uint32_t h1v = h2b[s1 * 8 + c2];
        float e = e0 + adv;
        float w = __expf(e >= 0.f ? e : 0.2f * e);
        w = ok0 ? w : 0.f;
        acc0 += w * bflo(h0);
        acc1 += w * bfhi(h0);
        dsum += w;
        e0 = e1; h0 = h1v; ok0 = ok1;
        s1 = s2; ok1 = ok2; idx1 = idx2;
    }
#pragma unroll
    for (int off = 8; off <= 32; off <<= 1) {
        acc0 += __shfl_xor(acc0, off, 64);
        acc1 += __shfl_xor(acc1, off, 64);
        dsum += __shfl_xor(dsum, off, 64);
    }
    float v0 = lrelu(acc0 / dsum + b2[2 * c2], 0.01f) * Wo[2 * c2];
    float v1 = lrelu(acc1 / dsum + b2[2 * c2 + 1], 0.01f) * Wo[2 * c2 + 1];
    float y = v0 + v1;
    y += __shfl_xor(y, 1, 64);
    y += __shfl_xor(y, 2, 64);
    y += __shfl_xor(y, 4, 64);
    if (lane == 0) out[n] = y + bo[0];
}

extern "C" void kernel_launch(void* const* d_in, const int* in_sizes, int n_in,
                              void* d_out, int out_size, void* d_ws, size_t ws_size,
                              hipStream_t stream) {
    const float* x    = (const float*)d_in[0];
    const int*   ei   = (const int*)d_in[1];
    const float* W1   = (const float*)d_in[2];
    const float* as1w = (const float*)d_in[3];
    const float* ad1w = (const float*)d_in[4];
    const float* b1   = (const float*)d_in[5];
    const float* W2   = (const float*)d_in[6];
    const float* as2w = (const float*)d_in[7];
    const float* ad2w = (const float*)d_in[8];
    const float* b2   = (const float*)d_in[9];
    const float* Wo   = (const float*)d_in[10];
    const float* bo   = (const float*)d_in[11];
    float* out = (float*)d_out;

    const int* srcp = ei;
    const int* dstp = ei + N_EDGES;

    char* p = (char*)d_ws;
    auto alloc = [&](size_t bytes) -> char* {
        char* r = p;
        p += (bytes + 255) / 256 * 256;
        return r;
    };
    // All gather indices s are real node ids (<50000) or clamped to 0 -> every
    // gather lands inside fully-initialized arrays; no pad-dependence.
    int*            bcur    = (int*)alloc((size_t)(NBUCKET + 1) * 4);
    int*            rowdesc = (int*)alloc((size_t)N_NODES * 4);
    uint32_t*       binned  = (uint32_t*)alloc((size_t)NBUCKET * CAP * 4);
    unsigned short* esrc    = (unsigned short*)alloc((size_t)NBUCKET * CAP * 2 + 256);
    uint32_t*       h2b     = (uint32_t*)alloc((size_t)N_NODES * 8 * 4);
    uint32_t*       h1b     = (uint32_t*)alloc((size_t)N_NODES * 32 * 4);
    float*          as1     = (float*)alloc((size_t)N_NODES * 4 * 4);
    float*          ad1     = (float*)alloc((size_t)N_NODES * 4 * 4);
    float*          as2     = (float*)alloc((size_t)N_NODES * 4);
    float*          ad2     = (float*)alloc((size_t)N_NODES * 4);

    hipMemsetAsync(bcur, 0, (size_t)(NBUCKET + 1) * 4, stream);

    k_pre<<<BIN_BLOCKS + GEMM_BLOCKS, 256, 0, stream>>>(x, W1, as1w, ad1w, h1b, as1, ad1,
                                                        srcp, dstp, bcur, binned);
    kB_sort<<<NBUCKET, 512, 0, stream>>>(bcur, binned, rowdesc, esrc);
    k_aggr1f<<<N_NODES / 4, 256, 0, stream>>>(rowdesc, esrc, as1, ad1, h1b, b1, W2, as2w, ad2w,
                                              h2b, as2, ad2);
    k_aggr2<<<N_NODES / 4, 256, 0, stream>>>(rowdesc, esrc, as2, ad2, h2b, b2, Wo, bo, out);
}

// Round 12
// 184.565 us; speedup vs baseline: 1.0515x; 1.0045x over previous
//
#include <hip/hip_runtime.h>
#include <hip/hip_bf16.h>
#include <cstdint>

#define N_NODES 50000
#define N_EDGES 1600000
#define EE (N_EDGES + N_NODES)
#define BSH 7
#define BSIZE 128
#define NBUCKET ((N_NODES + BSIZE - 1) >> BSH)   // 391
#define CSH 13
#define CAP 8192                                  // pow2 bucket capacity (mean fill 4224, sd ~65)
#define BIN_BLOCKS 403                            // ceil(EE/4096) -- one chunk per block
#define GEMM_BLOCKS 3125                          // 3125*16 == 50000

// HISTORY (hard-won, do not regress):
//  r4: per-edge direct scatter -> 102MB WRITE_SIZE (partial-line write amp). Two-stage LDS
//      binning IS the write-coalescer.
//  r5: NBUCKET=1563 (2.6-edge runs) -> 50MB WRITE_SIZE, +8us. NBUCKET=391/CHUNK=4096
//      (10.5-edge, 42B runs) is load-bearing.
//  r7: cross-block global cursors in the sort -> post-timing divergence. RULE: every read
//      rebuilt this-launch from the single zeroed root (bcur); no cross-block coordination.
//  r8: shuffle scan neutral -> sort is not barrier-bound.
//  r9: sort||GEMM overlap neutral. r6 grid is the anchor.
//  r10: 2-deep aggr pipeline (esrc +2, payload +1): 189.9 -> 185.4. Chain-hiding is the
//       live lever; aggr1f FETCH is at the ~64MB analytic ideal (no overfetch).
//  r11: deepen to 3-stage (index +3, payload +2) to cover L3-hit latency (~200cy), which
//       one iteration (~60-120cy) of lookahead cannot. [r11 run lost to infra; resubmitted]

__device__ __forceinline__ float lrelu(float x, float s) { return x >= 0.f ? x : s * x; }
__device__ __forceinline__ float bflo(uint32_t v) { return __uint_as_float(v << 16); }
__device__ __forceinline__ float bfhi(uint32_t v) { return __uint_as_float(v & 0xFFFF0000u); }
__device__ __forceinline__ uint32_t packbf(float a, float b) {
    uint32_t ua = __float_as_uint(a), ub = __float_as_uint(b);
    ua += 0x7FFF + ((ua >> 16) & 1);
    ub += 0x7FFF + ((ub >> 16) & 1);
    return (ua >> 16) | (ub & 0xFFFF0000u);
}
__device__ __forceinline__ float rdlane(float v, int l) {
    return __uint_as_float(__builtin_amdgcn_readlane(__float_as_uint(v), l));
}

// -------- Fused: edge binning (blocks 0..402, dispatched first) + layer-1 GEMM (rest) --------
__global__ __launch_bounds__(256) void k_pre(
    const float* __restrict__ x, const float* __restrict__ W1,
    const float* __restrict__ as_w, const float* __restrict__ ad_w,
    uint32_t* __restrict__ h1b, float* __restrict__ as1, float* __restrict__ ad1,
    const int* __restrict__ src, const int* __restrict__ dst,
    int* __restrict__ bcur, uint32_t* __restrict__ binned) {
    if (blockIdx.x < BIN_BLOCKS) {
        __shared__ int lcnt[NBUCKET];
        __shared__ int lbase[NBUCKET];
        const int T = 16;
        for (int i = threadIdx.x; i < NBUCKET; i += 256) lcnt[i] = 0;
        __syncthreads();
        uint32_t pv[T];
        uint32_t pm[T];
        int base = blockIdx.x * (256 * T);
        if (base + 256 * T <= N_EDGES) {
            // fast path: pure-edge chunk, int4 loads (4 edges per load)
            const int4* s4 = (const int4*)(src + base);
            const int4* d4 = (const int4*)(dst + base);
#pragma unroll
            for (int k = 0; k < 4; k++) {
                int4 sv = s4[threadIdx.x + k * 256];
                int4 dv = d4[threadIdx.x + k * 256];
                int ss[4] = {sv.x, sv.y, sv.z, sv.w};
                int dd[4] = {dv.x, dv.y, dv.z, dv.w};
#pragma unroll
                for (int j = 0; j < 4; j++) {
                    int b = dd[j] >> BSH;
                    int r = atomicAdd(&lcnt[b], 1);
                    pv[k * 4 + j] = (uint32_t)ss[j] | ((uint32_t)(dd[j] & (BSIZE - 1)) << 16);
                    pm[k * 4 + j] = (uint32_t)r | ((uint32_t)b << 16);
                }
            }
        } else {
#pragma unroll
            for (int k = 0; k < T; k++) {
                int e = base + ((k & 3) * 4 + (k >> 2)) * 256 + threadIdx.x;  // any order ok
                pm[k] = 0xFFFFFFFFu;
                if (e < EE) {
                    int s, d;
                    if (e < N_EDGES) { s = src[e]; d = dst[e]; } else { s = e - N_EDGES; d = s; }
                    int b = d >> BSH;
                    int r = atomicAdd(&lcnt[b], 1);
                    pv[k] = (uint32_t)s | ((uint32_t)(d & (BSIZE - 1)) << 16);
                    pm[k] = (uint32_t)r | ((uint32_t)b << 16);
                }
            }
        }
        __syncthreads();
        for (int i = threadIdx.x; i < NBUCKET; i += 256) {
            int c = lcnt[i];
            if (c) lbase[i] = atomicAdd(&bcur[i], c);
        }
        __syncthreads();
#pragma unroll
        for (int k = 0; k < T; k++) {
            if (pm[k] != 0xFFFFFFFFu) {
                int b = pm[k] >> 16, r = pm[k] & 0xFFFF;
                binned[((size_t)b << CSH) + lbase[b] + r] = pv[k];
            }
        }
        return;
    }
    // ---- layer-1 GEMM half: coalesced x load + readlane broadcast ----
    int c = threadIdx.x & 63;
    int wv = threadIdx.x >> 6;
    float wreg[64];
#pragma unroll
    for (int k = 0; k < 64; k++) wreg[k] = W1[k * 64 + c];
    float aw = as_w[c];
    float dw = ad_w[c];
    int base = (blockIdx.x - BIN_BLOCKS) * 16 + wv * 4;
#pragma unroll
    for (int r = 0; r < 4; r++) {
        int n = base + r;
        float xr = x[n * 64 + c];
        float a0 = 0.f, a1 = 0.f, a2 = 0.f, a3 = 0.f;
#pragma unroll
        for (int k = 0; k < 64; k += 4) {
            a0 = fmaf(rdlane(xr, k),     wreg[k],     a0);
            a1 = fmaf(rdlane(xr, k + 1), wreg[k + 1], a1);
            a2 = fmaf(rdlane(xr, k + 2), wreg[k + 2], a2);
            a3 = fmaf(rdlane(xr, k + 3), wreg[k + 3], a3);
        }
        float acc = (a0 + a1) + (a2 + a3);
        float other = __shfl_xor(acc, 1, 64);
        if (!(c & 1)) h1b[n * 32 + (c >> 1)] = packbf(acc, other);
        float asv = acc * aw;
        float adv = acc * dw;
#pragma unroll
        for (int off = 1; off < 16; off <<= 1) {
            asv += __shfl_xor(asv, off, 64);
            adv += __shfl_xor(adv, off, 64);
        }
        if ((c & 15) == 0) { as1[n * 4 + (c >> 4)] = asv; ad1[n * 4 + (c >> 4)] = adv; }
    }
}

// -------- Phase B: rank-capture counting sort -> u16 CSR src indices --------
// rowdesc[node] = off(13b) | deg(<<13);  esrc[pos] = src (u16)
__global__ __launch_bounds__(512) void kB_sort(const int* __restrict__ bcur, const uint32_t* __restrict__ binned,
                                               int* __restrict__ rowdesc, unsigned short* __restrict__ esrc) {
    int b = blockIdx.x, tid = threadIdx.x, wv = tid >> 6;
    int p0 = b << CSH;
    int L = bcur[b];
    __shared__ int cnt8[8][BSIZE];     // per-wave histograms
    __shared__ int wbase[8][BSIZE];
    __shared__ int shs[BSIZE];
    for (int i = tid; i < 8 * BSIZE; i += 512) ((int*)cnt8)[i] = 0;
    __syncthreads();

    uint32_t pv[16];
    unsigned short rk[16];
#pragma unroll
    for (int k = 0; k < 16; k++) {
        int i = tid + k * 512;
        if (i < L) {
            uint32_t v = binned[p0 + i];
            pv[k] = v;
            rk[k] = (unsigned short)atomicAdd(&cnt8[wv][(v >> 16) & (BSIZE - 1)], 1);
        }
    }
    __syncthreads();

    int tot = 0;
    if (tid < BSIZE) {
#pragma unroll
        for (int w = 0; w < 8; w++) tot += cnt8[w][tid];
        shs[tid] = tot;
    }
    __syncthreads();
    for (int off = 1; off < BSIZE; off <<= 1) {
        int t = 0;
        if (tid < BSIZE && tid >= off) t = shs[tid - off];
        __syncthreads();
        if (tid < BSIZE && tid >= off) shs[tid] += t;
        __syncthreads();
    }
    if (tid < BSIZE) {
        int excl = shs[tid] - tot;
        int node = (b << BSH) + tid;
        if (node < N_NODES) rowdesc[node] = excl | (tot << 13);
        int wb = excl;
#pragma unroll
        for (int w = 0; w < 8; w++) { wbase[w][tid] = wb; wb += cnt8[w][tid]; }
    }
    __syncthreads();

#pragma unroll
    for (int k = 0; k < 16; k++) {
        int i = tid + k * 512;
        if (i < L) {
            uint32_t v = pv[k];
            int dl = (v >> 16) & (BSIZE - 1);
            esrc[p0 + wbase[wv][dl] + (int)rk[k]] = (unsigned short)(v & 0xFFFF);
        }
    }
}

// -------- Layer 1 aggregation (inline weights) + fused L2 GEMM: 3-stage pipeline --------
// 12500 blocks, 1 node/wave. Masked tail lanes CLAMP s to 0 (never mask-by-weight a NaN gather).
// Pipeline: index prefetched +3, payload (as1/h1b) issued +2 -> two iterations (~120-240cy)
// of latency cover for L3-resident gathers. Named scalars only (no runtime-indexed arrays).
__global__ __launch_bounds__(256) void k_aggr1f(
    const int* __restrict__ rowdesc, const unsigned short* __restrict__ esrc,
    const float* __restrict__ as1, const float* __restrict__ ad1,
    const uint32_t* __restrict__ h1b,
    const float* __restrict__ b1, const float* __restrict__ W2,
    const float* __restrict__ as2w, const float* __restrict__ ad2w,
    uint32_t* __restrict__ h2b, float* __restrict__ as2, float* __restrict__ ad2) {
    int n = blockIdx.x * 4 + (threadIdx.x >> 6);
    int lane = threadIdx.x & 63;
    int md = rowdesc[n];
    int begin = ((n >> BSH) << CSH) + (md & (CAP - 1));
    int deg = md >> 13;

    int slot = lane >> 3, cl = lane & 7;   // edge slot = slot; lane covers channels 8cl..8cl+7
    int hc = cl >> 1;                      // head of these channels
    float ad1h = ad1[n * 4 + hc];

    const uint4* h1b4 = (const uint4*)h1b;
    float a0 = 0.f, a1 = 0.f, a2 = 0.f, a3 = 0.f, a4 = 0.f, a5 = 0.f, a6 = 0.f, a7 = 0.f, dsum = 0.f;

    int iters = (deg + 7) >> 3;
    // ---- prologue: payloads for it=0,1 in flight; index for it=2 ready ----
    bool ok0 = slot < deg;
    int idx1 = slot + 8;
    bool ok1 = idx1 < deg;
    int idx2 = slot + 16;
    bool ok2 = idx2 < deg;
    int s0 = ok0 ? (int)esrc[begin + slot] : 0;
    int s1 = ok1 ? (int)esrc[begin + idx1] : 0;
    int s2 = ok2 ? (int)esrc[begin + idx2] : 0;
    float e0 = as1[s0 * 4 + hc];
    uint4 v0 = h1b4[s0 * 8 + cl];
    float e1 = as1[s1 * 4 + hc];
    uint4 v1 = h1b4[s1 * 8 + cl];
#pragma unroll 2
    for (int it = 0; it < iters; it++) {
        // issue: index for it+3, payload for it+2 (clamped -> always safe)
        int idx3 = idx2 + 8;
        bool ok3 = idx3 < deg;
        int s3 = ok3 ? (int)esrc[begin + idx3] : 0;
        float e2 = as1[s2 * 4 + hc];
        uint4 v2 = h1b4[s2 * 8 + cl];
        // compute current (it)
        float e = e0 + ad1h;
        float w = __expf(e >= 0.f ? e : 0.2f * e);
        w = ok0 ? w : 0.f;
        dsum += w;
        a0 += w * bflo(v0.x); a1 += w * bfhi(v0.x);
        a2 += w * bflo(v0.y); a3 += w * bfhi(v0.y);
        a4 += w * bflo(v0.z); a5 += w * bfhi(v0.z);
        a6 += w * bflo(v0.w); a7 += w * bfhi(v0.w);
        // rotate
        e0 = e1; v0 = v1; ok0 = ok1;
        e1 = e2; v1 = v2; ok1 = ok2;
        s2 = s3; ok2 = ok3; idx2 = idx3;
    }
#pragma unroll
    for (int off = 8; off <= 32; off <<= 1) {
        a0 += __shfl_xor(a0, off, 64); a1 += __shfl_xor(a1, off, 64);
        a2 += __shfl_xor(a2, off, 64); a3 += __shfl_xor(a3, off, 64);
        a4 += __shfl_xor(a4, off, 64); a5 += __shfl_xor(a5, off, 64);
        a6 += __shfl_xor(a6, off, 64); a7 += __shfl_xor(a7, off, 64);
        dsum += __shfl_xor(dsum, off, 64);
    }
    float dinv = 1.f / dsum;               // full denom of head hc (deg>=1 via self-loop)

    float4 bb0 = *(const float4*)(b1 + 8 * cl);
    float4 bb1 = *(const float4*)(b1 + 8 * cl + 4);
    float act0 = lrelu(a0 * dinv + bb0.x, 0.01f);
    float act1 = lrelu(a1 * dinv + bb0.y, 0.01f);
    float act2 = lrelu(a2 * dinv + bb0.z, 0.01f);
    float act3 = lrelu(a3 * dinv + bb0.w, 0.01f);
    float act4 = lrelu(a4 * dinv + bb1.x, 0.01f);
    float act5 = lrelu(a5 * dinv + bb1.y, 0.01f);
    float act6 = lrelu(a6 * dinv + bb1.z, 0.01f);
    float act7 = lrelu(a7 * dinv + bb1.w, 0.01f);

    // fused L2 GEMM: lane (kg, co) sums k = 16kg..16kg+15 for output channel co
    int co = lane & 15, kg = lane >> 4;
    int l0 = 2 * kg, l1 = 2 * kg + 1;
    const float* w2r = W2 + (16 * kg) * 16 + co;
    float g = 0.f;
    g = fmaf(__shfl(act0, l0, 64), w2r[0 * 16],  g);
    g = fmaf(__shfl(act1, l0, 64), w2r[1 * 16],  g);
    g = fmaf(__shfl(act2, l0, 64), w2r[2 * 16],  g);
    g = fmaf(__shfl(act3, l0, 64), w2r[3 * 16],  g);
    g = fmaf(__shfl(act4, l0, 64), w2r[4 * 16],  g);
    g = fmaf(__shfl(act5, l0, 64), w2r[5 * 16],  g);
    g = fmaf(__shfl(act6, l0, 64), w2r[6 * 16],  g);
    g = fmaf(__shfl(act7, l0, 64), w2r[7 * 16],  g);
    g = fmaf(__shfl(act0, l1, 64), w2r[8 * 16],  g);
    g = fmaf(__shfl(act1, l1, 64), w2r[9 * 16],  g);
    g = fmaf(__shfl(act2, l1, 64), w2r[10 * 16], g);
    g = fmaf(__shfl(act3, l1, 64), w2r[11 * 16], g);
    g = fmaf(__shfl(act4, l1, 64), w2r[12 * 16], g);
    g = fmaf(__shfl(act5, l1, 64), w2r[13 * 16], g);
    g = fmaf(__shfl(act6, l1, 64), w2r[14 * 16], g);
    g = fmaf(__shfl(act7, l1, 64), w2r[15 * 16], g);
    g += __shfl_xor(g, 16, 64);
    g += __shfl_xor(g, 32, 64);
    // h2 packed bf16: even lanes <16 write channels (lane, lane+1)
    float godd = __shfl_xor(g, 1, 64);
    if (lane < 16 && !(lane & 1)) h2b[n * 8 + (lane >> 1)] = packbf(g, godd);
    float asv = g * as2w[co];
    float adv2 = g * ad2w[co];
#pragma unroll
    for (int off = 1; off < 16; off <<= 1) {
        asv += __shfl_xor(asv, off, 64);
        adv2 += __shfl_xor(adv2, off, 64);
    }
    if (lane == 0) { as2[n] = asv; ad2[n] = adv2; }
}

// -------- Layer 2 aggregation (inline weights, bf16 h2) + final linear: 3-stage pipeline ----
__global__ __launch_bounds__(256) void k_aggr2(
    const int* __restrict__ rowdesc, const unsigned short* __restrict__ esrc,
    const float* __restrict__ as2, const float* __restrict__ ad2,
    const uint32_t* __restrict__ h2b,
    const float* __restrict__ b2, const float* __restrict__ Wo,
    const float* __restrict__ bo, float* __restrict__ out) {
    int n = blockIdx.x * 4 + (threadIdx.x >> 6);
    int lane = threadIdx.x & 63;
    int md = rowdesc[n];
    int begin = ((n >> BSH) << CSH) + (md & (CAP - 1));
    int deg = md >> 13;
    float adv = ad2[n];

    int slot = lane >> 3, c2 = lane & 7;   // lane covers channels 2c2, 2c2+1
    float acc0 = 0.f, acc1 = 0.f, dsum = 0.f;

    int iters = (deg + 7) >> 3;
    bool ok0 = slot < deg;
    int idx1 = slot + 8;
    bool ok1 = idx1 < deg;
    int idx2 = slot + 16;
    bool ok2 = idx2 < deg;
    int s0 = ok0 ? (int)esrc[begin + slot] : 0;
    int s1 = ok1 ? (int)esrc[begin + idx1] : 0;
    int s2 = ok2 ? (int)esrc[begin + idx2] : 0;
    float e0 = as2[s0];
    uint32_t h0 = h2b[s0 * 8 + c2];
    float e1 = as2[s1];
    uint32_t h1v = h2b[s1 * 8 + c2];
#pragma unroll 2
    for (int it = 0; it < iters; it++) {
        int idx3 = idx2 + 8;
        bool ok3 = idx3 < deg;
        int s3 = ok3 ? (int)esrc[begin + idx3] : 0;
        float e2 = as2[s2];
        uint32_t h2v = h2b[s2 * 8 + c2];
        float e = e0 + adv;
        float w = __expf(e >= 0.f ? e : 0.2f * e);
        w = ok0 ? w : 0.f;
        acc0 += w * bflo(h0);
        acc1 += w * bfhi(h0);
        dsum += w;
        e0 = e1; h0 = h1v; ok0 = ok1;
        e1 = e2; h1v = h2v; ok1 = ok2;
        s2 = s3; ok2 = ok3; idx2 = idx3;
    }
#pragma unroll
    for (int off = 8; off <= 32; off <<= 1) {
        acc0 += __shfl_xor(acc0, off, 64);
        acc1 += __shfl_xor(acc1, off, 64);
        dsum += __shfl_xor(dsum, off, 64);
    }
    float v0 = lrelu(acc0 / dsum + b2[2 * c2], 0.01f) * Wo[2 * c2];
    float v1 = lrelu(acc1 / dsum + b2[2 * c2 + 1], 0.01f) * Wo[2 * c2 + 1];
    float y = v0 + v1;
    y += __shfl_xor(y, 1, 64);
    y += __shfl_xor(y, 2, 64);
    y += __shfl_xor(y, 4, 64);
    if (lane == 0) out[n] = y + bo[0];
}

extern "C" void kernel_launch(void* const* d_in, const int* in_sizes, int n_in,
                              void* d_out, int out_size, void* d_ws, size_t ws_size,
                              hipStream_t stream) {
    const float* x    = (const float*)d_in[0];
    const int*   ei   = (const int*)d_in[1];
    const float* W1   = (const float*)d_in[2];
    const float* as1w = (const float*)d_in[3];
    const float* ad1w = (const float*)d_in[4];
    const float* b1   = (const float*)d_in[5];
    const float* W2   = (const float*)d_in[6];
    const float* as2w = (const float*)d_in[7];
    const float* ad2w = (const float*)d_in[8];
    const float* b2   = (const float*)d_in[9];
    const float* Wo   = (const float*)d_in[10];
    const float* bo   = (const float*)d_in[11];
    float* out = (float*)d_out;

    const int* srcp = ei;
    const int* dstp = ei + N_EDGES;

    char* p = (char*)d_ws;
    auto alloc = [&](size_t bytes) -> char* {
        char* r = p;
        p += (bytes + 255) / 256 * 256;
        return r;
    };
    // All gather indices s are real node ids (<50000) or clamped to 0 -> every
    // gather lands inside fully-initialized arrays; no pad-dependence.
    int*            bcur    = (int*)alloc((size_t)(NBUCKET + 1) * 4);
    int*            rowdesc = (int*)alloc((size_t)N_NODES * 4);
    uint32_t*       binned  = (uint32_t*)alloc((size_t)NBUCKET * CAP * 4);
    unsigned short* esrc    = (unsigned short*)alloc((size_t)NBUCKET * CAP * 2 + 256);
    uint32_t*       h2b     = (uint32_t*)alloc((size_t)N_NODES * 8 * 4);
    uint32_t*       h1b     = (uint32_t*)alloc((size_t)N_NODES * 32 * 4);
    float*          as1     = (float*)alloc((size_t)N_NODES * 4 * 4);
    float*          ad1     = (float*)alloc((size_t)N_NODES * 4 * 4);
    float*          as2     = (float*)alloc((size_t)N_NODES * 4);
    float*          ad2     = (float*)alloc((size_t)N_NODES * 4);

    hipMemsetAsync(bcur, 0, (size_t)(NBUCKET + 1) * 4, stream);

    k_pre<<<BIN_BLOCKS + GEMM_BLOCKS, 256, 0, stream>>>(x, W1, as1w, ad1w, h1b, as1, ad1,
                                                        srcp, dstp, bcur, binned);
    kB_sort<<<NBUCKET, 512, 0, stream>>>(bcur, binned, rowdesc, esrc);
    k_aggr1f<<<N_NODES / 4, 256, 0, stream>>>(rowdesc, esrc, as1, ad1, h1b, b1, W2, as2w, ad2w,
                                              h2b, as2, ad2);
    k_aggr2<<<N_NODES / 4, 256, 0, stream>>>(rowdesc, esrc, as2, ad2, h2b, b2, Wo, bo, out);
}